// Round 1
// baseline (291.784 us; speedup 1.0000x reference)
//
#include <hip/hip_runtime.h>
#include <hip/hip_bf16.h>

// NV12 (4K) -> RGB at half resolution.
// byte_data: int32 (2160, 3840, 6). Flat view:
//   [0 : 4320*7680)            = full-res Y plane (4320, 7680)
//   [4320*7680 : end)          = interleaved UV plane (2160, 3840, 2)
// yuv = [Y[2i][2j], U[i][j], V[i][j]]; rgb[k] = sum_c (yuv[c]-off[c]) * M[c][k]
// out: float32 (2160, 3840, 3)

#define HALF_H 2160
#define HALF_W 3840
#define Y_ROW_STRIDE (2 * HALF_W * 2)      // 15360 int32 per 2 full-res rows
#define CHROMA_BASE (4320 * 7680)          // 33177600
#define QUADS_PER_ROW (HALF_W / 4)         // 960

__global__ __launch_bounds__(256) void nv12_to_rgb_kernel(
    const int* __restrict__ data,
    const float* __restrict__ M,     // 9 floats, row-major M[c][k]
    const float* __restrict__ off,   // 3 floats
    float* __restrict__ out)
{
    int tid = blockIdx.x * blockDim.x + threadIdx.x;   // one thread = 4 pixels
    const int nQuads = HALF_H * QUADS_PER_ROW;
    if (tid >= nQuads) return;

    int i  = tid / QUADS_PER_ROW;          // half-res row
    int jq = tid - i * QUADS_PER_ROW;
    int j  = jq * 4;                       // half-res col (multiple of 4)

    // --- loads (all 16B aligned, coalesced across the wave) ---
    // Y: full-res row 2i, cols 2j..2j+7 (use even elements)
    const int4* yp = (const int4*)(data + (size_t)Y_ROW_STRIDE * i + 2 * j);
    int4 y0 = yp[0];
    int4 y1 = yp[1];
    // UV: 4 interleaved pairs
    const int4* cp = (const int4*)(data + (size_t)CHROMA_BASE + ((size_t)i * HALF_W + j) * 2);
    int4 c0 = cp[0];
    int4 c1 = cp[1];

    // uniform coefficient loads (scalar-cached)
    float m00 = M[0], m01 = M[1], m02 = M[2];
    float m10 = M[3], m11 = M[4], m12 = M[5];
    float m20 = M[6], m21 = M[7], m22 = M[8];
    float o0 = off[0], o1 = off[1], o2 = off[2];

    float ys[4] = {(float)y0.x, (float)y0.z, (float)y1.x, (float)y1.z};
    float us[4] = {(float)c0.x, (float)c0.z, (float)c1.x, (float)c1.z};
    float vs[4] = {(float)c0.y, (float)c0.w, (float)c1.y, (float)c1.w};

    float4 ov[3];
    float* o = (float*)ov;
    #pragma unroll
    for (int p = 0; p < 4; ++p) {
        float Y = ys[p] - o0;
        float U = us[p] - o1;
        float V = vs[p] - o2;
        o[p * 3 + 0] = Y * m00 + U * m10 + V * m20;
        o[p * 3 + 1] = Y * m01 + U * m11 + V * m21;
        o[p * 3 + 2] = Y * m02 + U * m12 + V * m22;
    }

    float4* op = (float4*)(out + ((size_t)i * HALF_W + j) * 3);
    op[0] = ov[0];
    op[1] = ov[1];
    op[2] = ov[2];
}

extern "C" void kernel_launch(void* const* d_in, const int* in_sizes, int n_in,
                              void* d_out, int out_size, void* d_ws, size_t ws_size,
                              hipStream_t stream) {
    const int*   data = (const int*)d_in[0];
    const float* M    = (const float*)d_in[1];
    const float* off  = (const float*)d_in[2];
    float*       out  = (float*)d_out;

    const int nQuads = HALF_H * QUADS_PER_ROW;   // 2,073,600 threads
    dim3 block(256);
    dim3 grid((nQuads + 255) / 256);             // 8100 blocks
    nv12_to_rgb_kernel<<<grid, block, 0, stream>>>(data, M, off, out);
}

// Round 2
// 290.948 us; speedup vs baseline: 1.0029x; 1.0029x over previous
//
#include <hip/hip_runtime.h>
#include <hip/hip_bf16.h>

// NV12 (4K) -> RGB at half resolution.
// byte_data: int32 (2160, 3840, 6). Flat view:
//   [0 : 4320*7680)   = full-res Y plane (4320, 7680) -> subsample [::2, ::2]
//   [4320*7680 : end) = interleaved UV plane (2160, 3840, 2)
// rgb[k] = sum_c (yuv[c]-off[c]) * M[c][k];  out: float32 (2160, 3840, 3)
//
// Strategy: one thread = 4 consecutive pixels (flat index; 3840%4==0 so a quad
// never crosses a row). Inputs loaded as aligned int4 (32B lane stride; the
// 2x line touch is absorbed by L1). Output staged through 12 KB LDS so the
// final global stores are lane-unit-stride float4 (8 full 128B lines per
// store instruction instead of 24 partial lines).

#define HALF_H 2160
#define HALF_W 3840
#define Y_ROW_STRIDE (2 * HALF_W * 2)      // 15360 int32 per full-res row pair
#define CHROMA_BASE (4320 * 7680)          // 33177600
#define PIX_PER_BLOCK 1024                 // 256 threads x 4 px
#define F4_PER_BLOCK (PIX_PER_BLOCK * 3 / 4)  // 768

__global__ __launch_bounds__(256) void nv12_to_rgb_kernel(
    const int* __restrict__ data,
    const float* __restrict__ M,     // 9 floats, row-major M[c][k]
    const float* __restrict__ off,   // 3 floats
    float* __restrict__ out)
{
    __shared__ float4 lds[F4_PER_BLOCK];   // 12 KB

    const int t  = threadIdx.x;
    const int p0 = blockIdx.x * PIX_PER_BLOCK + t * 4;  // first of 4 pixels

    int i = p0 / HALF_W;           // half-res row (magic-mul)
    int j = p0 - i * HALF_W;       // half-res col, multiple of 4

    // --- aligned vector loads ---
    const int4* yp = (const int4*)(data + (size_t)Y_ROW_STRIDE * i + 2 * j);
    int4 y0 = yp[0];
    int4 y1 = yp[1];
    const int4* cp = (const int4*)(data + (size_t)CHROMA_BASE + ((size_t)i * HALF_W + j) * 2);
    int4 c0 = cp[0];
    int4 c1 = cp[1];

    // uniform coefficients (scalar-cached)
    float m00 = M[0], m01 = M[1], m02 = M[2];
    float m10 = M[3], m11 = M[4], m12 = M[5];
    float m20 = M[6], m21 = M[7], m22 = M[8];
    float o0 = off[0], o1 = off[1], o2 = off[2];

    float ys[4] = {(float)y0.x, (float)y0.z, (float)y1.x, (float)y1.z};
    float us[4] = {(float)c0.x, (float)c0.z, (float)c1.x, (float)c1.z};
    float vs[4] = {(float)c0.y, (float)c0.w, (float)c1.y, (float)c1.w};

    float4 ov[3];
    float* o = (float*)ov;
    #pragma unroll
    for (int p = 0; p < 4; ++p) {
        float Y = ys[p] - o0;
        float U = us[p] - o1;
        float V = vs[p] - o2;
        o[p * 3 + 0] = Y * m00 + U * m10 + V * m20;
        o[p * 3 + 1] = Y * m01 + U * m11 + V * m21;
        o[p * 3 + 2] = Y * m02 + U * m12 + V * m22;
    }

    // stage to LDS (bank-even: 12t mod 32 covers all 32 banks uniformly)
    #pragma unroll
    for (int k = 0; k < 3; ++k) lds[3 * t + k] = ov[k];

    __syncthreads();

    // unit-stride cooperative writeback: 64 lanes x 16B = 8 full lines/instr
    float4* ob = (float4*)out + (size_t)blockIdx.x * F4_PER_BLOCK;
    #pragma unroll
    for (int k = 0; k < 3; ++k) {
        int q = k * 256 + t;
        ob[q] = lds[q];
    }
}

extern "C" void kernel_launch(void* const* d_in, const int* in_sizes, int n_in,
                              void* d_out, int out_size, void* d_ws, size_t ws_size,
                              hipStream_t stream) {
    const int*   data = (const int*)d_in[0];
    const float* M    = (const float*)d_in[1];
    const float* off  = (const float*)d_in[2];
    float*       out  = (float*)d_out;

    const int nPix = HALF_H * HALF_W;                 // 8,294,400
    dim3 block(256);
    dim3 grid(nPix / PIX_PER_BLOCK);                  // 8100 blocks
    nv12_to_rgb_kernel<<<grid, block, 0, stream>>>(data, M, off, out);
}

// Round 3
// 287.575 us; speedup vs baseline: 1.0146x; 1.0117x over previous
//
#include <hip/hip_runtime.h>
#include <hip/hip_bf16.h>

// NV12 (4K) -> RGB at half resolution.
// byte_data: int32 (2160, 3840, 6). Flat view:
//   [0 : 4320*7680)   = full-res Y plane (4320, 7680) -> subsample [::2, ::2]
//   [4320*7680 : end) = interleaved UV plane (2160, 3840, 2)
// rgb[k] = sum_c (yuv[c]-off[c]) * M[c][k];  out: float32 (2160, 3840, 3)
//
// Strategy (round 3): one thread = 2 consecutive pixels, so BOTH input loads
// are exactly one int4 at unit lane stride (16 full 64B lines per wave
// instruction, zero transaction inflation):
//   Y:  row 2i, cols 2j..2j+3  -> int4, use .x/.z
//   UV: pairs (u,v) for j,j+1  -> int4 = (u0,v0,u1,v1)
// Output (24 B/thread, unaligned for float4) regroups through 6 KB LDS into
// lane-unit-stride float4 global stores.

#define HALF_H 2160
#define HALF_W 3840
#define Y_ROW_STRIDE (2 * HALF_W * 2)      // 15360 int32 per full-res row pair
#define CHROMA_BASE (4320 * 7680)          // 33177600
#define PIX_PER_BLOCK 512                  // 256 threads x 2 px
#define F4_PER_BLOCK (PIX_PER_BLOCK * 3 / 4)  // 384

__global__ __launch_bounds__(256) void nv12_to_rgb_kernel(
    const int* __restrict__ data,
    const float* __restrict__ M,     // 9 floats, row-major M[c][k]
    const float* __restrict__ off,   // 3 floats
    float* __restrict__ out)
{
    __shared__ float4 lds[F4_PER_BLOCK];   // 6 KB

    const int t  = threadIdx.x;
    const int p0 = blockIdx.x * PIX_PER_BLOCK + t * 2;  // first of 2 pixels

    const int i = p0 / HALF_W;             // half-res row
    const int j = p0 - i * HALF_W;         // half-res col, multiple of 2

    // --- unit-stride aligned vector loads ---
    int4 y = *(const int4*)(data + (size_t)Y_ROW_STRIDE * i + 2 * j);
    int4 c = *(const int4*)(data + (size_t)CHROMA_BASE + ((size_t)i * HALF_W + j) * 2);

    // uniform coefficients (scalar-cached)
    float m00 = M[0], m01 = M[1], m02 = M[2];
    float m10 = M[3], m11 = M[4], m12 = M[5];
    float m20 = M[6], m21 = M[7], m22 = M[8];
    float o0 = off[0], o1 = off[1], o2 = off[2];

    float ys[2] = {(float)y.x, (float)y.z};
    float us[2] = {(float)c.x, (float)c.z};
    float vs[2] = {(float)c.y, (float)c.w};

    float o6[6];
    #pragma unroll
    for (int p = 0; p < 2; ++p) {
        float Y = ys[p] - o0;
        float U = us[p] - o1;
        float V = vs[p] - o2;
        o6[p * 3 + 0] = Y * m00 + U * m10 + V * m20;
        o6[p * 3 + 1] = Y * m01 + U * m11 + V * m21;
        o6[p * 3 + 2] = Y * m02 + U * m12 + V * m22;
    }

    // stage to LDS as three float2 (ds_write_b64, stride 24B -> 4-way max,
    // ~free on this tiny traffic)
    float2* l2 = (float2*)lds;
    #pragma unroll
    for (int k = 0; k < 3; ++k)
        l2[3 * t + k] = make_float2(o6[2 * k], o6[2 * k + 1]);

    __syncthreads();

    // unit-stride cooperative writeback: 384 float4 per block
    float4* ob = (float4*)out + (size_t)blockIdx.x * F4_PER_BLOCK;
    for (int q = t; q < F4_PER_BLOCK; q += 256)
        ob[q] = lds[q];
}

extern "C" void kernel_launch(void* const* d_in, const int* in_sizes, int n_in,
                              void* d_out, int out_size, void* d_ws, size_t ws_size,
                              hipStream_t stream) {
    const int*   data = (const int*)d_in[0];
    const float* M    = (const float*)d_in[1];
    const float* off  = (const float*)d_in[2];
    float*       out  = (float*)d_out;

    const int nPix = HALF_H * HALF_W;                 // 8,294,400
    dim3 block(256);
    dim3 grid(nPix / PIX_PER_BLOCK);                  // 16200 blocks
    nv12_to_rgb_kernel<<<grid, block, 0, stream>>>(data, M, off, out);
}